// Round 6
// baseline (183.832 us; speedup 1.0000x reference)
//
#include <hip/hip_runtime.h>

typedef unsigned short u16;
typedef unsigned int u32;
typedef __attribute__((ext_vector_type(8))) short short8;   // bf16x8 MFMA frag
typedef __attribute__((ext_vector_type(4))) float f32x4;    // MFMA acc frag

// Problem constants (match reference)
constexpr int NODES = 100000;
constexpr int EDGES = 800000;
constexpr int DIM = 128;       // node dim
constexpr int EDIM = 8;        // edge attr dim
constexpr int HEADS = 8;

// counting-sort scan geometry
constexpr int SCAN_BLK = 512;
constexpr int NSCAN_BLKS = (NODES + SCAN_BLK - 1) / SCAN_BLK;  // 196
constexpr int NPAD = NSCAN_BLKS * SCAN_BLK;                    // 100352

__device__ inline u16 f2bf(float f) {              // f32 -> bf16 RNE
    u32 u = __float_as_uint(f);
    u = (u + 0x7FFFu + ((u >> 16) & 1u)) >> 16;
    return (u16)u;
}
__device__ inline float bf2f(u16 s) {              // bf16 -> f32 exact
    return __uint_as_float(((u32)s) << 16);
}
__device__ inline u32 packbf(float a, float b) {
    return (u32)f2bf(a) | ((u32)f2bf(b) << 16);
}

// ---------------------------------------------------------------------------
// Convert W_node (128x128 f32, row-major W[n][k]) to bf16. No transpose: the
// MFMA B-fragment wants B[k][n] = W[n][k], i.e. contiguous k within a row.
// ---------------------------------------------------------------------------
__global__ __launch_bounds__(256) void convert_w(const float* __restrict__ W,
                                                 u16* __restrict__ Wb) {
    int i = blockIdx.x * 256 + threadIdx.x;   // 64 blocks
    Wb[i] = f2bf(W[i]);
}

// ---------------------------------------------------------------------------
// node_proj via MFMA (proven in R4): xp_bf16 = bf16(x @ W.T + b).
// ---------------------------------------------------------------------------
__global__ __launch_bounds__(256) void node_proj_mfma(const float* __restrict__ x,
                                                      const u16* __restrict__ Wb,
                                                      const float* __restrict__ bn,
                                                      u16* __restrict__ xpb) {
    __shared__ u16 sW[128 * 136];   // 34816 B, +8 pad per row

    const int tid = threadIdx.x;
    {   // stage W: 128 rows x 16 chunks of 8 bf16 (16B)
        const short8* g = reinterpret_cast<const short8*>(Wb);
        #pragma unroll
        for (int i = tid; i < 128 * 16; i += 256) {
            int row = i >> 4, ch = i & 15;
            *reinterpret_cast<short8*>(&sW[row * 136 + ch * 8]) = g[row * 16 + ch];
        }
    }
    __syncthreads();

    const int w = tid >> 6;        // wave 0..3
    const int l = tid & 63;
    const int lr = l & 15;
    const int lh = l >> 4;
    const int m0 = blockIdx.x * 128 + w * 32;

    f32x4 acc[2][8];
    #pragma unroll
    for (int mt = 0; mt < 2; ++mt)
        #pragma unroll
        for (int nt = 0; nt < 8; ++nt) acc[mt][nt] = f32x4{0, 0, 0, 0};

    #pragma unroll
    for (int kk = 0; kk < 4; ++kk) {
        const int kb = kk * 32 + lh * 8;
        short8 a0, a1;
        {
            int row = m0 + lr;  row = row < NODES ? row : 0;
            const float* p = x + (size_t)row * DIM + kb;
            float4 f0 = *reinterpret_cast<const float4*>(p);
            float4 f1 = *reinterpret_cast<const float4*>(p + 4);
            a0[0]=f2bf(f0.x); a0[1]=f2bf(f0.y); a0[2]=f2bf(f0.z); a0[3]=f2bf(f0.w);
            a0[4]=f2bf(f1.x); a0[5]=f2bf(f1.y); a0[6]=f2bf(f1.z); a0[7]=f2bf(f1.w);
        }
        {
            int row = m0 + 16 + lr;  row = row < NODES ? row : 0;
            const float* p = x + (size_t)row * DIM + kb;
            float4 f0 = *reinterpret_cast<const float4*>(p);
            float4 f1 = *reinterpret_cast<const float4*>(p + 4);
            a1[0]=f2bf(f0.x); a1[1]=f2bf(f0.y); a1[2]=f2bf(f0.z); a1[3]=f2bf(f0.w);
            a1[4]=f2bf(f1.x); a1[5]=f2bf(f1.y); a1[6]=f2bf(f1.z); a1[7]=f2bf(f1.w);
        }
        #pragma unroll
        for (int nt = 0; nt < 8; ++nt) {
            short8 b = *reinterpret_cast<const short8*>(&sW[(nt * 16 + lr) * 136 + kb]);
            acc[0][nt] = __builtin_amdgcn_mfma_f32_16x16x32_bf16(a0, b, acc[0][nt], 0, 0, 0);
            acc[1][nt] = __builtin_amdgcn_mfma_f32_16x16x32_bf16(a1, b, acc[1][nt], 0, 0, 0);
        }
    }

    float bias[8];
    #pragma unroll
    for (int nt = 0; nt < 8; ++nt) bias[nt] = bn[nt * 16 + lr];

    #pragma unroll
    for (int mt = 0; mt < 2; ++mt) {
        #pragma unroll
        for (int r = 0; r < 4; ++r) {
            int grow = m0 + mt * 16 + lh * 4 + r;
            if (grow < NODES) {
                #pragma unroll
                for (int nt = 0; nt < 8; ++nt)
                    xpb[(size_t)grow * DIM + nt * 16 + lr] =
                        f2bf(acc[mt][nt][r] + bias[nt]);
            }
        }
    }
}

// ---------------------------------------------------------------------------
// Counting sort of edges by target node (proven)
// ---------------------------------------------------------------------------
__global__ __launch_bounds__(256) void hist_kernel(const int* __restrict__ ei,
                                                   int* __restrict__ cnt) {
    int e = blockIdx.x * 256 + threadIdx.x;
    if (e < EDGES) atomicAdd(&cnt[ei[EDGES + e]], 1);
}

__global__ __launch_bounds__(256) void scan_block_sums(const int* __restrict__ cnt,
                                                       int* __restrict__ partial) {
    __shared__ int sd[256];
    int b = blockIdx.x, t = threadIdx.x;
    int s = cnt[b * SCAN_BLK + t] + cnt[b * SCAN_BLK + 256 + t];
    sd[t] = s; __syncthreads();
    for (int d = 128; d > 0; d >>= 1) {
        if (t < d) sd[t] += sd[t + d];
        __syncthreads();
    }
    if (t == 0) partial[b] = sd[0];
}

__global__ __launch_bounds__(256) void scan_partials(int* __restrict__ partial) {
    __shared__ int sd[256];
    int t = threadIdx.x;
    int v = (t < NSCAN_BLKS) ? partial[t] : 0;
    sd[t] = v; __syncthreads();
    for (int d = 1; d < 256; d <<= 1) {
        int u = (t >= d) ? sd[t - d] : 0;
        __syncthreads();
        sd[t] += u;
        __syncthreads();
    }
    if (t < NSCAN_BLKS) partial[t] = sd[t] - v;   // exclusive
}

__global__ __launch_bounds__(256) void scan_write(const int* __restrict__ cnt,
                                                  const int* __restrict__ partial,
                                                  int* __restrict__ start) {
    __shared__ int sd[256];
    int b = blockIdx.x, t = threadIdx.x;
    int i0 = b * SCAN_BLK + 2 * t;
    int c0 = cnt[i0], c1 = cnt[i0 + 1];
    int s = c0 + c1;
    sd[t] = s; __syncthreads();
    for (int d = 1; d < 256; d <<= 1) {
        int u = (t >= d) ? sd[t - d] : 0;
        __syncthreads();
        sd[t] += u;
        __syncthreads();
    }
    int excl = sd[t] - s + partial[b];
    start[i0] = excl;
    start[i0 + 1] = excl + c0;
}

// ---------------------------------------------------------------------------
// scatter_ids (R1-proven): minimal 4B scattered payload. Mutates start so
// start[n] becomes the segment END for node n.
// ---------------------------------------------------------------------------
__global__ __launch_bounds__(256) void scatter_ids(const int* __restrict__ ei,
                                                   int* __restrict__ start,
                                                   int* __restrict__ sortedE) {
    int e = blockIdx.x * 256 + threadIdx.x;
    if (e < EDGES) {
        int p = atomicAdd(&start[ei[EDGES + e]], 1);
        sortedE[p] = e;
    }
}

// ---------------------------------------------------------------------------
// gate_gather: thread t = sorted position. Sequential read of sortedE,
// random GATHER of ei[e] / ea[e] (L3-resident, latency-hidden), coalesced
// writes of srcS[t] (4B) and gateS[t] (16B, bf16x8). No scattered stores.
// ---------------------------------------------------------------------------
__global__ __launch_bounds__(256) void gate_gather(const int* __restrict__ sortedE,
                                                   const int* __restrict__ ei,
                                                   const float* __restrict__ ea,
                                                   const float* __restrict__ We,
                                                   const float* __restrict__ be,
                                                   int* __restrict__ srcS,
                                                   uint4* __restrict__ gateS) {
    __shared__ float sW[HEADS * EDIM];
    __shared__ float sb[HEADS];
    if (threadIdx.x < HEADS * EDIM) sW[threadIdx.x] = We[threadIdx.x];
    if (threadIdx.x < HEADS) sb[threadIdx.x] = be[threadIdx.x];
    __syncthreads();

    const int t = blockIdx.x * 256 + threadIdx.x;
    if (t >= EDGES) return;

    const int e = sortedE[t];                     // sequential
    const int src = ei[e];                        // random 4B gather
    float4 a0 = *reinterpret_cast<const float4*>(ea + (size_t)e * EDIM);      // random 32B
    float4 a1 = *reinterpret_cast<const float4*>(ea + (size_t)e * EDIM + 4);

    float g[HEADS];
    #pragma unroll
    for (int h = 0; h < HEADS; ++h) {
        const float* w = &sW[h * EDIM];
        float z = sb[h]
                + a0.x * w[0] + a0.y * w[1] + a0.z * w[2] + a0.w * w[3]
                + a1.x * w[4] + a1.y * w[5] + a1.z * w[6] + a1.w * w[7];
        g[h] = 1.0f / (1.0f + __expf(-z));
    }

    uint4 gw;
    gw.x = packbf(g[0], g[1]);
    gw.y = packbf(g[2], g[3]);
    gw.z = packbf(g[4], g[5]);
    gw.w = packbf(g[6], g[7]);
    srcS[t] = src;          // coalesced
    gateS[t] = gw;          // coalesced 16B
}

// ---------------------------------------------------------------------------
// Aggregate v4: 32-lane group per node; srcS/gateS sequential streams, one
// random hop (xpb gather). Lane's gate = 2B broadcast load.
// ---------------------------------------------------------------------------
__global__ __launch_bounds__(256) void aggregate_v4(const u16* __restrict__ xpb,
                                                    const int* __restrict__ startM,
                                                    const int* __restrict__ srcS,
                                                    const u16* __restrict__ gateS,
                                                    float* __restrict__ out) {
    const int n = blockIdx.x * 8 + (threadIdx.x >> 5);
    if (n >= NODES) return;
    const int l = threadIdx.x & 31;
    const int h = l >> 2;

    int j = (n == 0) ? 0 : startM[n - 1];
    const int jend = startM[n];

    float4 acc = {0, 0, 0, 0};

    for (; j + 4 <= jend; j += 4) {
        int s0 = srcS[j + 0], s1 = srcS[j + 1], s2 = srcS[j + 2], s3 = srcS[j + 3];
        float g0 = bf2f(gateS[(size_t)(j + 0) * HEADS + h]);
        float g1 = bf2f(gateS[(size_t)(j + 1) * HEADS + h]);
        float g2 = bf2f(gateS[(size_t)(j + 2) * HEADS + h]);
        float g3 = bf2f(gateS[(size_t)(j + 3) * HEADS + h]);
        ushort4 u0 = *reinterpret_cast<const ushort4*>(xpb + (size_t)s0 * DIM + l * 4);
        ushort4 u1 = *reinterpret_cast<const ushort4*>(xpb + (size_t)s1 * DIM + l * 4);
        ushort4 u2 = *reinterpret_cast<const ushort4*>(xpb + (size_t)s2 * DIM + l * 4);
        ushort4 u3 = *reinterpret_cast<const ushort4*>(xpb + (size_t)s3 * DIM + l * 4);
        acc.x += g0 * bf2f(u0.x); acc.y += g0 * bf2f(u0.y);
        acc.z += g0 * bf2f(u0.z); acc.w += g0 * bf2f(u0.w);
        acc.x += g1 * bf2f(u1.x); acc.y += g1 * bf2f(u1.y);
        acc.z += g1 * bf2f(u1.z); acc.w += g1 * bf2f(u1.w);
        acc.x += g2 * bf2f(u2.x); acc.y += g2 * bf2f(u2.y);
        acc.z += g2 * bf2f(u2.z); acc.w += g2 * bf2f(u2.w);
        acc.x += g3 * bf2f(u3.x); acc.y += g3 * bf2f(u3.y);
        acc.z += g3 * bf2f(u3.z); acc.w += g3 * bf2f(u3.w);
    }
    for (; j < jend; ++j) {
        int s0 = srcS[j];
        float g0 = bf2f(gateS[(size_t)j * HEADS + h]);
        ushort4 u0 = *reinterpret_cast<const ushort4*>(xpb + (size_t)s0 * DIM + l * 4);
        acc.x += g0 * bf2f(u0.x); acc.y += g0 * bf2f(u0.y);
        acc.z += g0 * bf2f(u0.z); acc.w += g0 * bf2f(u0.w);
    }

    reinterpret_cast<float4*>(out)[(size_t)n * 32 + l] = acc;
}

// ---------------------------------------------------------------------------
// Fallback (small ws): per-edge atomic scatter reading bf16 xp
// ---------------------------------------------------------------------------
__global__ __launch_bounds__(256) void edge_scatter(const int* __restrict__ ei,
                                                    const float* __restrict__ ea,
                                                    const float* __restrict__ We,
                                                    const float* __restrict__ be,
                                                    const u16* __restrict__ xpb,
                                                    float* __restrict__ out) {
    __shared__ float sW[HEADS * EDIM];
    __shared__ float sb[HEADS];
    if (threadIdx.x < HEADS * EDIM) sW[threadIdx.x] = We[threadIdx.x];
    if (threadIdx.x < HEADS) sb[threadIdx.x] = be[threadIdx.x];
    __syncthreads();

    const int t = blockIdx.x * 256 + threadIdx.x;
    const int e = t >> 5;
    const int l = t & 31;
    if (e >= EDGES) return;

    const int src = ei[e];
    const int tgt = ei[EDGES + e];
    const int h = l >> 2;

    float4 ea0 = *reinterpret_cast<const float4*>(ea + (size_t)e * EDIM);
    float4 ea1 = *reinterpret_cast<const float4*>(ea + (size_t)e * EDIM + 4);
    float4 wa = *reinterpret_cast<const float4*>(&sW[h * EDIM]);
    float4 wb = *reinterpret_cast<const float4*>(&sW[h * EDIM + 4]);
    float z = sb[h]
            + ea0.x * wa.x + ea0.y * wa.y + ea0.z * wa.z + ea0.w * wa.w
            + ea1.x * wb.x + ea1.y * wb.y + ea1.z * wb.z + ea1.w * wb.w;
    float g = 1.0f / (1.0f + __expf(-z));

    ushort4 u = *reinterpret_cast<const ushort4*>(xpb + (size_t)src * DIM + l * 4);
    float* op = out + (size_t)tgt * DIM + l * 4;
    unsafeAtomicAdd(op + 0, bf2f(u.x) * g);
    unsafeAtomicAdd(op + 1, bf2f(u.y) * g);
    unsafeAtomicAdd(op + 2, bf2f(u.z) * g);
    unsafeAtomicAdd(op + 3, bf2f(u.w) * g);
}

// ---------------------------------------------------------------------------
extern "C" void kernel_launch(void* const* d_in, const int* in_sizes, int n_in,
                              void* d_out, int out_size, void* d_ws, size_t ws_size,
                              hipStream_t stream) {
    const float* x   = (const float*)d_in[0];
    const int*   ei  = (const int*)d_in[1];
    const float* eat = (const float*)d_in[2];
    const float* Wn  = (const float*)d_in[3];
    const float* bn  = (const float*)d_in[4];
    const float* We  = (const float*)d_in[5];
    const float* be  = (const float*)d_in[6];
    float* out = (float*)d_out;

    // workspace layout
    u16* Wb  = (u16*)d_ws;                                  // 16384 bf16 (32KB)
    u16* xpb = Wb + DIM * DIM;                              // NODES*128 bf16 (25.6MB)
    int* cnt     = (int*)(xpb + (size_t)NODES * DIM);       // NPAD i32
    int* start   = cnt + NPAD;                              // NPAD i32
    int* partial = start + NPAD;                            // 256 i32
    int* sortedE = partial + 256;                           // EDGES i32 (3.2MB)
    int* srcS    = sortedE + EDGES;                         // EDGES i32 (3.2MB)
    u16* gateS   = (u16*)(srcS + EDGES);                    // EDGES*8 bf16 (12.8MB)

    const size_t need = (size_t)(DIM * DIM) * 2 + (size_t)NODES * DIM * 2
                      + (size_t)(2 * NPAD + 256) * 4
                      + (size_t)EDGES * 4 * 2 + (size_t)EDGES * HEADS * 2;  // ~45.7 MB

    convert_w<<<64, 256, 0, stream>>>(Wn, Wb);
    node_proj_mfma<<<(NODES + 127) / 128, 256, 0, stream>>>(x, Wb, bn, xpb);

    if (ws_size >= need) {
        hipMemsetAsync(cnt, 0, (size_t)NPAD * sizeof(int), stream);
        hist_kernel<<<(EDGES + 255) / 256, 256, 0, stream>>>(ei, cnt);
        scan_block_sums<<<NSCAN_BLKS, 256, 0, stream>>>(cnt, partial);
        scan_partials<<<1, 256, 0, stream>>>(partial);
        scan_write<<<NSCAN_BLKS, 256, 0, stream>>>(cnt, partial, start);
        scatter_ids<<<(EDGES + 255) / 256, 256, 0, stream>>>(ei, start, sortedE);
        gate_gather<<<(EDGES + 255) / 256, 256, 0, stream>>>(sortedE, ei, eat,
                                                             We, be, srcS,
                                                             (uint4*)gateS);
        aggregate_v4<<<(NODES + 7) / 8, 256, 0, stream>>>(xpb, start, srcS,
                                                          gateS, out);
    } else {
        hipMemsetAsync(d_out, 0, (size_t)out_size * sizeof(float), stream);
        edge_scatter<<<(EDGES * 32) / 256, 256, 0, stream>>>(ei, eat, We, be, xpb, out);
    }
}

// Round 7
// 148.243 us; speedup vs baseline: 1.2401x; 1.2401x over previous
//
#include <hip/hip_runtime.h>

typedef unsigned short u16;
typedef unsigned int u32;
typedef __attribute__((ext_vector_type(8))) short short8;   // bf16x8 MFMA frag
typedef __attribute__((ext_vector_type(4))) float f32x4;    // MFMA acc frag

// Problem constants (match reference)
constexpr int NODES = 100000;
constexpr int EDGES = 800000;
constexpr int DIM = 128;       // node dim
constexpr int EDIM = 8;        // edge attr dim
constexpr int HEADS = 8;

__device__ inline u16 f2bf(float f) {              // f32 -> bf16 RNE
    u32 u = __float_as_uint(f);
    u = (u + 0x7FFFu + ((u >> 16) & 1u)) >> 16;
    return (u16)u;
}
__device__ inline float bf2f(u16 s) {              // bf16 -> f32 exact
    return __uint_as_float(((u32)s) << 16);
}
__device__ inline u32 packbf(float a, float b) {
    return (u32)f2bf(a) | ((u32)f2bf(b) << 16);
}

// ---------------------------------------------------------------------------
// Convert W_node (128x128 f32, row-major W[n][k]) to bf16. No transpose: the
// MFMA B-fragment wants B[k][n] = W[n][k], i.e. contiguous k within a row.
// ---------------------------------------------------------------------------
__global__ __launch_bounds__(256) void convert_w(const float* __restrict__ W,
                                                 u16* __restrict__ Wb) {
    int i = blockIdx.x * 256 + threadIdx.x;   // 64 blocks
    Wb[i] = f2bf(W[i]);
}

// ---------------------------------------------------------------------------
// node_proj via MFMA (proven since R4): xp_bf16 = bf16(x @ W.T + b).
// ---------------------------------------------------------------------------
__global__ __launch_bounds__(256) void node_proj_mfma(const float* __restrict__ x,
                                                      const u16* __restrict__ Wb,
                                                      const float* __restrict__ bn,
                                                      u16* __restrict__ xpb) {
    __shared__ u16 sW[128 * 136];   // 34816 B, +8 pad per row

    const int tid = threadIdx.x;
    {   // stage W: 128 rows x 16 chunks of 8 bf16 (16B)
        const short8* g = reinterpret_cast<const short8*>(Wb);
        #pragma unroll
        for (int i = tid; i < 128 * 16; i += 256) {
            int row = i >> 4, ch = i & 15;
            *reinterpret_cast<short8*>(&sW[row * 136 + ch * 8]) = g[row * 16 + ch];
        }
    }
    __syncthreads();

    const int w = tid >> 6;        // wave 0..3
    const int l = tid & 63;
    const int lr = l & 15;
    const int lh = l >> 4;
    const int m0 = blockIdx.x * 128 + w * 32;

    f32x4 acc[2][8];
    #pragma unroll
    for (int mt = 0; mt < 2; ++mt)
        #pragma unroll
        for (int nt = 0; nt < 8; ++nt) acc[mt][nt] = f32x4{0, 0, 0, 0};

    #pragma unroll
    for (int kk = 0; kk < 4; ++kk) {
        const int kb = kk * 32 + lh * 8;
        short8 a0, a1;
        {
            int row = m0 + lr;  row = row < NODES ? row : 0;
            const float* p = x + (size_t)row * DIM + kb;
            float4 f0 = *reinterpret_cast<const float4*>(p);
            float4 f1 = *reinterpret_cast<const float4*>(p + 4);
            a0[0]=f2bf(f0.x); a0[1]=f2bf(f0.y); a0[2]=f2bf(f0.z); a0[3]=f2bf(f0.w);
            a0[4]=f2bf(f1.x); a0[5]=f2bf(f1.y); a0[6]=f2bf(f1.z); a0[7]=f2bf(f1.w);
        }
        {
            int row = m0 + 16 + lr;  row = row < NODES ? row : 0;
            const float* p = x + (size_t)row * DIM + kb;
            float4 f0 = *reinterpret_cast<const float4*>(p);
            float4 f1 = *reinterpret_cast<const float4*>(p + 4);
            a1[0]=f2bf(f0.x); a1[1]=f2bf(f0.y); a1[2]=f2bf(f0.z); a1[3]=f2bf(f0.w);
            a1[4]=f2bf(f1.x); a1[5]=f2bf(f1.y); a1[6]=f2bf(f1.z); a1[7]=f2bf(f1.w);
        }
        #pragma unroll
        for (int nt = 0; nt < 8; ++nt) {
            short8 b = *reinterpret_cast<const short8*>(&sW[(nt * 16 + lr) * 136 + kb]);
            acc[0][nt] = __builtin_amdgcn_mfma_f32_16x16x32_bf16(a0, b, acc[0][nt], 0, 0, 0);
            acc[1][nt] = __builtin_amdgcn_mfma_f32_16x16x32_bf16(a1, b, acc[1][nt], 0, 0, 0);
        }
    }

    float bias[8];
    #pragma unroll
    for (int nt = 0; nt < 8; ++nt) bias[nt] = bn[nt * 16 + lr];

    #pragma unroll
    for (int mt = 0; mt < 2; ++mt) {
        #pragma unroll
        for (int r = 0; r < 4; ++r) {
            int grow = m0 + mt * 16 + lh * 4 + r;
            if (grow < NODES) {
                #pragma unroll
                for (int nt = 0; nt < 8; ++nt)
                    xpb[(size_t)grow * DIM + nt * 16 + lr] =
                        f2bf(acc[mt][nt][r] + bias[nt]);
            }
        }
    }
}

// ---------------------------------------------------------------------------
// build_links: per-target linked lists. next[e] written COALESCED at index e;
// only head[] (400KB, L2-resident) takes random atomics. No scattered stores.
// ---------------------------------------------------------------------------
__global__ __launch_bounds__(256) void build_links(const int* __restrict__ ei,
                                                   int* __restrict__ head,
                                                   int* __restrict__ next) {
    int e = blockIdx.x * 256 + threadIdx.x;
    if (e < EDGES) {
        int tgt = ei[EDGES + e];
        next[e] = atomicExch(&head[tgt], e);
    }
}

// ---------------------------------------------------------------------------
// gate_compute: fully coalesced per-edge gates -> gateE[e] (16B, bf16x8).
// ---------------------------------------------------------------------------
__global__ __launch_bounds__(256) void gate_compute(const float* __restrict__ ea,
                                                    const float* __restrict__ We,
                                                    const float* __restrict__ be,
                                                    uint4* __restrict__ gateE) {
    __shared__ float sW[HEADS * EDIM];
    __shared__ float sb[HEADS];
    if (threadIdx.x < HEADS * EDIM) sW[threadIdx.x] = We[threadIdx.x];
    if (threadIdx.x < HEADS) sb[threadIdx.x] = be[threadIdx.x];
    __syncthreads();

    const int e = blockIdx.x * 256 + threadIdx.x;
    if (e >= EDGES) return;

    float4 a0 = *reinterpret_cast<const float4*>(ea + (size_t)e * EDIM);
    float4 a1 = *reinterpret_cast<const float4*>(ea + (size_t)e * EDIM + 4);

    float g[HEADS];
    #pragma unroll
    for (int h = 0; h < HEADS; ++h) {
        const float* w = &sW[h * EDIM];
        float z = sb[h]
                + a0.x * w[0] + a0.y * w[1] + a0.z * w[2] + a0.w * w[3]
                + a1.x * w[4] + a1.y * w[5] + a1.z * w[6] + a1.w * w[7];
        g[h] = 1.0f / (1.0f + __expf(-z));
    }

    uint4 gw;
    gw.x = packbf(g[0], g[1]);
    gw.y = packbf(g[2], g[3]);
    gw.z = packbf(g[4], g[5]);
    gw.w = packbf(g[6], g[7]);
    gateE[e] = gw;          // coalesced 16B
}

// ---------------------------------------------------------------------------
// aggregate_ll: 32-lane group per node walks the target's edge list.
// Serial dependence per hop = next[e] (4B, L2-resident). ei[e], gateE[e],
// and xpb[src] issue in parallel once e is known. Group's 32 lanes read the
// xpb row as a coalesced 256B burst; out store coalesced float4.
// ---------------------------------------------------------------------------
__global__ __launch_bounds__(256) void aggregate_ll(const u16* __restrict__ xpb,
                                                    const int* __restrict__ head,
                                                    const int* __restrict__ next,
                                                    const int* __restrict__ ei,
                                                    const u16* __restrict__ gateE,
                                                    float* __restrict__ out) {
    const int n = blockIdx.x * 8 + (threadIdx.x >> 5);
    if (n >= NODES) return;
    const int l = threadIdx.x & 31;
    const int h = l >> 2;

    float4 acc = {0, 0, 0, 0};

    int e = head[n];
    while (e >= 0) {
        int nx = next[e];                         // the only serial dep
        int src = ei[e];                          // parallel with nx
        float g = bf2f(gateE[(size_t)e * HEADS + h]);
        ushort4 u = *reinterpret_cast<const ushort4*>(xpb + (size_t)src * DIM + l * 4);
        acc.x += g * bf2f(u.x);
        acc.y += g * bf2f(u.y);
        acc.z += g * bf2f(u.z);
        acc.w += g * bf2f(u.w);
        e = nx;
    }

    reinterpret_cast<float4*>(out)[(size_t)n * 32 + l] = acc;
}

// ---------------------------------------------------------------------------
// Fallback (small ws): per-edge atomic scatter reading bf16 xp
// ---------------------------------------------------------------------------
__global__ __launch_bounds__(256) void edge_scatter(const int* __restrict__ ei,
                                                    const float* __restrict__ ea,
                                                    const float* __restrict__ We,
                                                    const float* __restrict__ be,
                                                    const u16* __restrict__ xpb,
                                                    float* __restrict__ out) {
    __shared__ float sW[HEADS * EDIM];
    __shared__ float sb[HEADS];
    if (threadIdx.x < HEADS * EDIM) sW[threadIdx.x] = We[threadIdx.x];
    if (threadIdx.x < HEADS) sb[threadIdx.x] = be[threadIdx.x];
    __syncthreads();

    const int t = blockIdx.x * 256 + threadIdx.x;
    const int e = t >> 5;
    const int l = t & 31;
    if (e >= EDGES) return;

    const int src = ei[e];
    const int tgt = ei[EDGES + e];
    const int h = l >> 2;

    float4 ea0 = *reinterpret_cast<const float4*>(ea + (size_t)e * EDIM);
    float4 ea1 = *reinterpret_cast<const float4*>(ea + (size_t)e * EDIM + 4);
    float4 wa = *reinterpret_cast<const float4*>(&sW[h * EDIM]);
    float4 wb = *reinterpret_cast<const float4*>(&sW[h * EDIM + 4]);
    float z = sb[h]
            + ea0.x * wa.x + ea0.y * wa.y + ea0.z * wa.z + ea0.w * wa.w
            + ea1.x * wb.x + ea1.y * wb.y + ea1.z * wb.z + ea1.w * wb.w;
    float g = 1.0f / (1.0f + __expf(-z));

    ushort4 u = *reinterpret_cast<const ushort4*>(xpb + (size_t)src * DIM + l * 4);
    float* op = out + (size_t)tgt * DIM + l * 4;
    unsafeAtomicAdd(op + 0, bf2f(u.x) * g);
    unsafeAtomicAdd(op + 1, bf2f(u.y) * g);
    unsafeAtomicAdd(op + 2, bf2f(u.z) * g);
    unsafeAtomicAdd(op + 3, bf2f(u.w) * g);
}

// ---------------------------------------------------------------------------
extern "C" void kernel_launch(void* const* d_in, const int* in_sizes, int n_in,
                              void* d_out, int out_size, void* d_ws, size_t ws_size,
                              hipStream_t stream) {
    const float* x   = (const float*)d_in[0];
    const int*   ei  = (const int*)d_in[1];
    const float* eat = (const float*)d_in[2];
    const float* Wn  = (const float*)d_in[3];
    const float* bn  = (const float*)d_in[4];
    const float* We  = (const float*)d_in[5];
    const float* be  = (const float*)d_in[6];
    float* out = (float*)d_out;

    // workspace layout (all segments 16B-aligned)
    u16* Wb   = (u16*)d_ws;                                 // 16384 bf16 (32KB)
    u16* xpb  = Wb + DIM * DIM;                             // NODES*128 bf16 (25.6MB)
    int* head = (int*)(xpb + (size_t)NODES * DIM);          // NODES i32 (400KB)
    int* next = head + NODES;                               // EDGES i32 (3.2MB)
    u16* gateE = (u16*)(next + EDGES);                      // EDGES*8 bf16 (12.8MB)

    const size_t need = (size_t)(DIM * DIM) * 2 + (size_t)NODES * DIM * 2
                      + (size_t)NODES * 4 + (size_t)EDGES * 4
                      + (size_t)EDGES * HEADS * 2;          // ~42.1 MB

    convert_w<<<64, 256, 0, stream>>>(Wn, Wb);
    node_proj_mfma<<<(NODES + 127) / 128, 256, 0, stream>>>(x, Wb, bn, xpb);

    if (ws_size >= need) {
        hipMemsetAsync(head, 0xFF, (size_t)NODES * sizeof(int), stream);  // head = -1
        build_links<<<(EDGES + 255) / 256, 256, 0, stream>>>(ei, head, next);
        gate_compute<<<(EDGES + 255) / 256, 256, 0, stream>>>(eat, We, be,
                                                              (uint4*)gateE);
        aggregate_ll<<<(NODES + 7) / 8, 256, 0, stream>>>(xpb, head, next, ei,
                                                          gateE, out);
    } else {
        hipMemsetAsync(d_out, 0, (size_t)out_size * sizeof(float), stream);
        edge_scatter<<<(EDGES * 32) / 256, 256, 0, stream>>>(ei, eat, We, be, xpb, out);
    }
}

// Round 8
// 121.161 us; speedup vs baseline: 1.5173x; 1.2235x over previous
//
#include <hip/hip_runtime.h>

typedef unsigned short u16;
typedef unsigned int u32;
typedef __attribute__((ext_vector_type(8))) short short8;   // bf16x8 MFMA frag
typedef __attribute__((ext_vector_type(4))) float f32x4;    // MFMA acc frag

// Problem constants (match reference)
constexpr int NODES = 100000;
constexpr int EDGES = 800000;
constexpr int DIM = 128;       // node dim
constexpr int EDIM = 8;        // edge attr dim
constexpr int HEADS = 8;

__device__ inline u16 f2bf(float f) {              // f32 -> bf16 RNE
    u32 u = __float_as_uint(f);
    u = (u + 0x7FFFu + ((u >> 16) & 1u)) >> 16;
    return (u16)u;
}
__device__ inline float bf2f(u16 s) {              // bf16 -> f32 exact
    return __uint_as_float(((u32)s) << 16);
}
__device__ inline u32 packbf(float a, float b) {
    return (u32)f2bf(a) | ((u32)f2bf(b) << 16);
}

// ---------------------------------------------------------------------------
// Convert W_node (128x128 f32, row-major W[n][k]) to bf16. No transpose: the
// MFMA B-fragment wants B[k][n] = W[n][k], i.e. contiguous k within a row.
// ---------------------------------------------------------------------------
__global__ __launch_bounds__(256) void convert_w(const float* __restrict__ W,
                                                 u16* __restrict__ Wb) {
    int i = blockIdx.x * 256 + threadIdx.x;   // 64 blocks
    Wb[i] = f2bf(W[i]);
}

// ---------------------------------------------------------------------------
// node_proj via MFMA (proven since R4): xp_bf16 = bf16(x @ W.T + b).
// ---------------------------------------------------------------------------
__global__ __launch_bounds__(256) void node_proj_mfma(const float* __restrict__ x,
                                                      const u16* __restrict__ Wb,
                                                      const float* __restrict__ bn,
                                                      u16* __restrict__ xpb) {
    __shared__ u16 sW[128 * 136];   // 34816 B, +8 pad per row

    const int tid = threadIdx.x;
    {   // stage W: 128 rows x 16 chunks of 8 bf16 (16B)
        const short8* g = reinterpret_cast<const short8*>(Wb);
        #pragma unroll
        for (int i = tid; i < 128 * 16; i += 256) {
            int row = i >> 4, ch = i & 15;
            *reinterpret_cast<short8*>(&sW[row * 136 + ch * 8]) = g[row * 16 + ch];
        }
    }
    __syncthreads();

    const int w = tid >> 6;        // wave 0..3
    const int l = tid & 63;
    const int lr = l & 15;
    const int lh = l >> 4;
    const int m0 = blockIdx.x * 128 + w * 32;

    f32x4 acc[2][8];
    #pragma unroll
    for (int mt = 0; mt < 2; ++mt)
        #pragma unroll
        for (int nt = 0; nt < 8; ++nt) acc[mt][nt] = f32x4{0, 0, 0, 0};

    #pragma unroll
    for (int kk = 0; kk < 4; ++kk) {
        const int kb = kk * 32 + lh * 8;
        short8 a0, a1;
        {
            int row = m0 + lr;  row = row < NODES ? row : 0;
            const float* p = x + (size_t)row * DIM + kb;
            float4 f0 = *reinterpret_cast<const float4*>(p);
            float4 f1 = *reinterpret_cast<const float4*>(p + 4);
            a0[0]=f2bf(f0.x); a0[1]=f2bf(f0.y); a0[2]=f2bf(f0.z); a0[3]=f2bf(f0.w);
            a0[4]=f2bf(f1.x); a0[5]=f2bf(f1.y); a0[6]=f2bf(f1.z); a0[7]=f2bf(f1.w);
        }
        {
            int row = m0 + 16 + lr;  row = row < NODES ? row : 0;
            const float* p = x + (size_t)row * DIM + kb;
            float4 f0 = *reinterpret_cast<const float4*>(p);
            float4 f1 = *reinterpret_cast<const float4*>(p + 4);
            a1[0]=f2bf(f0.x); a1[1]=f2bf(f0.y); a1[2]=f2bf(f0.z); a1[3]=f2bf(f0.w);
            a1[4]=f2bf(f1.x); a1[5]=f2bf(f1.y); a1[6]=f2bf(f1.z); a1[7]=f2bf(f1.w);
        }
        #pragma unroll
        for (int nt = 0; nt < 8; ++nt) {
            short8 b = *reinterpret_cast<const short8*>(&sW[(nt * 16 + lr) * 136 + kb]);
            acc[0][nt] = __builtin_amdgcn_mfma_f32_16x16x32_bf16(a0, b, acc[0][nt], 0, 0, 0);
            acc[1][nt] = __builtin_amdgcn_mfma_f32_16x16x32_bf16(a1, b, acc[1][nt], 0, 0, 0);
        }
    }

    float bias[8];
    #pragma unroll
    for (int nt = 0; nt < 8; ++nt) bias[nt] = bn[nt * 16 + lr];

    #pragma unroll
    for (int mt = 0; mt < 2; ++mt) {
        #pragma unroll
        for (int r = 0; r < 4; ++r) {
            int grow = m0 + mt * 16 + lh * 4 + r;
            if (grow < NODES) {
                #pragma unroll
                for (int nt = 0; nt < 8; ++nt)
                    xpb[(size_t)grow * DIM + nt * 16 + lr] =
                        f2bf(acc[mt][nt][r] + bias[nt]);
            }
        }
    }
}

// ---------------------------------------------------------------------------
// build_rec: fused link-build + gate precompute. One coalesced per-edge pass.
// Record (32B, coalesced write at index e):
//   [0,4): next  [4,8): src  [8,24): 8 gates bf16  [24,32): pad
// Only head[] (400KB, L2-resident) takes random atomics.
// ---------------------------------------------------------------------------
__global__ __launch_bounds__(256) void build_rec(const int* __restrict__ ei,
                                                 const float* __restrict__ ea,
                                                 const float* __restrict__ We,
                                                 const float* __restrict__ be,
                                                 int* __restrict__ head,
                                                 uint4* __restrict__ rec) {
    __shared__ float sW[HEADS * EDIM];
    __shared__ float sb[HEADS];
    if (threadIdx.x < HEADS * EDIM) sW[threadIdx.x] = We[threadIdx.x];
    if (threadIdx.x < HEADS) sb[threadIdx.x] = be[threadIdx.x];
    __syncthreads();

    const int e = blockIdx.x * 256 + threadIdx.x;
    if (e >= EDGES) return;

    const int src = ei[e];
    const int tgt = ei[EDGES + e];
    float4 a0 = *reinterpret_cast<const float4*>(ea + (size_t)e * EDIM);
    float4 a1 = *reinterpret_cast<const float4*>(ea + (size_t)e * EDIM + 4);

    float g[HEADS];
    #pragma unroll
    for (int h = 0; h < HEADS; ++h) {
        const float* w = &sW[h * EDIM];
        float z = sb[h]
                + a0.x * w[0] + a0.y * w[1] + a0.z * w[2] + a0.w * w[3]
                + a1.x * w[4] + a1.y * w[5] + a1.z * w[6] + a1.w * w[7];
        g[h] = 1.0f / (1.0f + __expf(-z));
    }

    int nx = atomicExch(&head[tgt], e);

    uint4 r0, r1;
    r0.x = (u32)nx;
    r0.y = (u32)src;
    r0.z = packbf(g[0], g[1]);
    r0.w = packbf(g[2], g[3]);
    r1.x = packbf(g[4], g[5]);
    r1.y = packbf(g[6], g[7]);
    r1.z = 0; r1.w = 0;
    rec[(size_t)e * 2 + 0] = r0;      // coalesced 32B
    rec[(size_t)e * 2 + 1] = r1;
}

// ---------------------------------------------------------------------------
// aggregate_v6: 16-lane group per node (lane owns 8 cols = ushort8, 16B —
// coalescing sweet spot; 4 groups/wave doubles in-flight chains vs 32-lane).
// Per hop: ONE metadata line (int2 + 2B gate, same 64B line) + the xpb row.
// ---------------------------------------------------------------------------
__global__ __launch_bounds__(256) void aggregate_v6(const u16* __restrict__ xpb,
                                                    const int* __restrict__ head,
                                                    const char* __restrict__ recB,
                                                    float* __restrict__ out) {
    const int n = blockIdx.x * 16 + (threadIdx.x >> 4);
    if (n >= NODES) return;
    const int l = threadIdx.x & 15;    // lane in group
    const int h = l >> 1;              // head = cols [8l,8l+8) / 16

    float acc[8];
    #pragma unroll
    for (int i = 0; i < 8; ++i) acc[i] = 0.0f;

    int e = head[n];
    while (e >= 0) {
        const char* r = recB + (size_t)e * 32;
        int2 ns = *reinterpret_cast<const int2*>(r);              // next, src
        float g = bf2f(*reinterpret_cast<const u16*>(r + 8 + 2 * h));
        short8 u = *reinterpret_cast<const short8*>(
            xpb + (size_t)ns.y * DIM + l * 8);                    // 16B of row
        #pragma unroll
        for (int i = 0; i < 8; ++i) acc[i] += g * bf2f((u16)u[i]);
        e = ns.x;
    }

    float4 o0 = {acc[0], acc[1], acc[2], acc[3]};
    float4 o1 = {acc[4], acc[5], acc[6], acc[7]};
    float4* op = reinterpret_cast<float4*>(out + (size_t)n * DIM + l * 8);
    op[0] = o0;
    op[1] = o1;
}

// ---------------------------------------------------------------------------
// Fallback (small ws): per-edge atomic scatter reading bf16 xp
// ---------------------------------------------------------------------------
__global__ __launch_bounds__(256) void edge_scatter(const int* __restrict__ ei,
                                                    const float* __restrict__ ea,
                                                    const float* __restrict__ We,
                                                    const float* __restrict__ be,
                                                    const u16* __restrict__ xpb,
                                                    float* __restrict__ out) {
    __shared__ float sW[HEADS * EDIM];
    __shared__ float sb[HEADS];
    if (threadIdx.x < HEADS * EDIM) sW[threadIdx.x] = We[threadIdx.x];
    if (threadIdx.x < HEADS) sb[threadIdx.x] = be[threadIdx.x];
    __syncthreads();

    const int t = blockIdx.x * 256 + threadIdx.x;
    const int e = t >> 5;
    const int l = t & 31;
    if (e >= EDGES) return;

    const int src = ei[e];
    const int tgt = ei[EDGES + e];
    const int h = l >> 2;

    float4 ea0 = *reinterpret_cast<const float4*>(ea + (size_t)e * EDIM);
    float4 ea1 = *reinterpret_cast<const float4*>(ea + (size_t)e * EDIM + 4);
    float4 wa = *reinterpret_cast<const float4*>(&sW[h * EDIM]);
    float4 wb = *reinterpret_cast<const float4*>(&sW[h * EDIM + 4]);
    float z = sb[h]
            + ea0.x * wa.x + ea0.y * wa.y + ea0.z * wa.z + ea0.w * wa.w
            + ea1.x * wb.x + ea1.y * wb.y + ea1.z * wb.z + ea1.w * wb.w;
    float g = 1.0f / (1.0f + __expf(-z));

    ushort4 u = *reinterpret_cast<const ushort4*>(xpb + (size_t)src * DIM + l * 4);
    float* op = out + (size_t)tgt * DIM + l * 4;
    unsafeAtomicAdd(op + 0, bf2f(u.x) * g);
    unsafeAtomicAdd(op + 1, bf2f(u.y) * g);
    unsafeAtomicAdd(op + 2, bf2f(u.z) * g);
    unsafeAtomicAdd(op + 3, bf2f(u.w) * g);
}

// ---------------------------------------------------------------------------
extern "C" void kernel_launch(void* const* d_in, const int* in_sizes, int n_in,
                              void* d_out, int out_size, void* d_ws, size_t ws_size,
                              hipStream_t stream) {
    const float* x   = (const float*)d_in[0];
    const int*   ei  = (const int*)d_in[1];
    const float* eat = (const float*)d_in[2];
    const float* Wn  = (const float*)d_in[3];
    const float* bn  = (const float*)d_in[4];
    const float* We  = (const float*)d_in[5];
    const float* be  = (const float*)d_in[6];
    float* out = (float*)d_out;

    // workspace layout (all segments 16B-aligned)
    u16* Wb   = (u16*)d_ws;                                 // 16384 bf16 (32KB)
    u16* xpb  = Wb + DIM * DIM;                             // NODES*128 bf16 (25.6MB)
    int* head = (int*)(xpb + (size_t)NODES * DIM);          // NODES i32 (400KB)
    char* rec = (char*)(head + NODES);                      // EDGES*32 B (25.6MB)

    const size_t need = (size_t)(DIM * DIM) * 2 + (size_t)NODES * DIM * 2
                      + (size_t)NODES * 4 + (size_t)EDGES * 32;   // ~51.7 MB

    convert_w<<<64, 256, 0, stream>>>(Wn, Wb);
    node_proj_mfma<<<(NODES + 127) / 128, 256, 0, stream>>>(x, Wb, bn, xpb);

    if (ws_size >= need) {
        hipMemsetAsync(head, 0xFF, (size_t)NODES * sizeof(int), stream);  // head = -1
        build_rec<<<(EDGES + 255) / 256, 256, 0, stream>>>(ei, eat, We, be,
                                                           head, (uint4*)rec);
        aggregate_v6<<<(NODES + 15) / 16, 256, 0, stream>>>(xpb, head, rec, out);
    } else {
        hipMemsetAsync(d_out, 0, (size_t)out_size * sizeof(float), stream);
        edge_scatter<<<(EDGES * 32) / 256, 256, 0, stream>>>(ei, eat, We, be, xpb, out);
    }
}

// Round 9
// 112.364 us; speedup vs baseline: 1.6360x; 1.0783x over previous
//
#include <hip/hip_runtime.h>

typedef unsigned short u16;
typedef unsigned int u32;
typedef __attribute__((ext_vector_type(8))) short short8;   // bf16x8 MFMA frag
typedef __attribute__((ext_vector_type(4))) float f32x4;    // MFMA acc frag

// Problem constants (match reference)
constexpr int NODES = 100000;
constexpr int EDGES = 800000;
constexpr int DIM = 128;       // node dim
constexpr int EDIM = 8;        // edge attr dim
constexpr int HEADS = 8;

constexpr int PROJ_BLOCKS = (NODES + 127) / 128;   // 782
constexpr int REC_BLOCKS  = (EDGES + 255) / 256;   // 3125

__device__ inline u16 f2bf(float f) {              // f32 -> bf16 RNE
    u32 u = __float_as_uint(f);
    u = (u + 0x7FFFu + ((u >> 16) & 1u)) >> 16;
    return (u16)u;
}
__device__ inline float bf2f(u16 s) {              // bf16 -> f32 exact
    return __uint_as_float(((u32)s) << 16);
}
__device__ inline u32 packbf(float a, float b) {
    return (u32)f2bf(a) | ((u32)f2bf(b) << 16);
}

// ---------------------------------------------------------------------------
// prep_fused: blocks [0,PROJ_BLOCKS) = node_proj via MFMA (W staged f32->bf16
// inline); blocks [PROJ_BLOCKS, ...) = build_rec (link-build + gate, coalesced
// 32B record). The two phases are independent and overlap in one dispatch.
// Record layout: [0,4): next  [4,8): src  [8,24): 8 gates bf16  [24,32): pad
// 4-way split lists: head4[tgt*4 + (e&3)] -> 4 chains/node, mean len 2.
// ---------------------------------------------------------------------------
__global__ __launch_bounds__(256) void prep_fused(const float* __restrict__ x,
                                                  const float* __restrict__ Wn,
                                                  const float* __restrict__ bn,
                                                  const int* __restrict__ ei,
                                                  const float* __restrict__ ea,
                                                  const float* __restrict__ We,
                                                  const float* __restrict__ be,
                                                  int* __restrict__ head4,
                                                  uint4* __restrict__ rec,
                                                  u16* __restrict__ xpb) {
    __shared__ u16 sLds[128 * 136];   // 34816 B (proj); rec path reuses 288 B

    const int tid = threadIdx.x;

    if (blockIdx.x < PROJ_BLOCKS) {
        // ---------------- node_proj path (proven R4 structure) ----------------
        {   // stage W: f32 global -> bf16 LDS, 128 rows x 16 chunks of 8
            #pragma unroll
            for (int i = tid; i < 128 * 16; i += 256) {
                int row = i >> 4, ch = i & 15;
                const float* p = Wn + row * DIM + ch * 8;
                float4 f0 = *reinterpret_cast<const float4*>(p);
                float4 f1 = *reinterpret_cast<const float4*>(p + 4);
                short8 v;
                v[0]=(short)f2bf(f0.x); v[1]=(short)f2bf(f0.y);
                v[2]=(short)f2bf(f0.z); v[3]=(short)f2bf(f0.w);
                v[4]=(short)f2bf(f1.x); v[5]=(short)f2bf(f1.y);
                v[6]=(short)f2bf(f1.z); v[7]=(short)f2bf(f1.w);
                *reinterpret_cast<short8*>(&sLds[row * 136 + ch * 8]) = v;
            }
        }
        __syncthreads();

        const int w = tid >> 6;        // wave 0..3
        const int l = tid & 63;
        const int lr = l & 15;
        const int lh = l >> 4;
        const int m0 = blockIdx.x * 128 + w * 32;

        f32x4 acc[2][8];
        #pragma unroll
        for (int mt = 0; mt < 2; ++mt)
            #pragma unroll
            for (int nt = 0; nt < 8; ++nt) acc[mt][nt] = f32x4{0, 0, 0, 0};

        #pragma unroll
        for (int kk = 0; kk < 4; ++kk) {
            const int kb = kk * 32 + lh * 8;
            short8 a0, a1;
            {
                int row = m0 + lr;  row = row < NODES ? row : 0;
                const float* p = x + (size_t)row * DIM + kb;
                float4 f0 = *reinterpret_cast<const float4*>(p);
                float4 f1 = *reinterpret_cast<const float4*>(p + 4);
                a0[0]=(short)f2bf(f0.x); a0[1]=(short)f2bf(f0.y);
                a0[2]=(short)f2bf(f0.z); a0[3]=(short)f2bf(f0.w);
                a0[4]=(short)f2bf(f1.x); a0[5]=(short)f2bf(f1.y);
                a0[6]=(short)f2bf(f1.z); a0[7]=(short)f2bf(f1.w);
            }
            {
                int row = m0 + 16 + lr;  row = row < NODES ? row : 0;
                const float* p = x + (size_t)row * DIM + kb;
                float4 f0 = *reinterpret_cast<const float4*>(p);
                float4 f1 = *reinterpret_cast<const float4*>(p + 4);
                a1[0]=(short)f2bf(f0.x); a1[1]=(short)f2bf(f0.y);
                a1[2]=(short)f2bf(f0.z); a1[3]=(short)f2bf(f0.w);
                a1[4]=(short)f2bf(f1.x); a1[5]=(short)f2bf(f1.y);
                a1[6]=(short)f2bf(f1.z); a1[7]=(short)f2bf(f1.w);
            }
            #pragma unroll
            for (int nt = 0; nt < 8; ++nt) {
                short8 b = *reinterpret_cast<const short8*>(&sLds[(nt * 16 + lr) * 136 + kb]);
                acc[0][nt] = __builtin_amdgcn_mfma_f32_16x16x32_bf16(a0, b, acc[0][nt], 0, 0, 0);
                acc[1][nt] = __builtin_amdgcn_mfma_f32_16x16x32_bf16(a1, b, acc[1][nt], 0, 0, 0);
            }
        }

        float bias[8];
        #pragma unroll
        for (int nt = 0; nt < 8; ++nt) bias[nt] = bn[nt * 16 + lr];

        #pragma unroll
        for (int mt = 0; mt < 2; ++mt) {
            #pragma unroll
            for (int r = 0; r < 4; ++r) {
                int grow = m0 + mt * 16 + lh * 4 + r;
                if (grow < NODES) {
                    #pragma unroll
                    for (int nt = 0; nt < 8; ++nt)
                        xpb[(size_t)grow * DIM + nt * 16 + lr] =
                            f2bf(acc[mt][nt][r] + bias[nt]);
                }
            }
        }
    } else {
        // ---------------- build_rec path ----------------
        float* sW = reinterpret_cast<float*>(sLds);      // 64 f32
        float* sb = sW + HEADS * EDIM;                   // 8 f32
        if (tid < HEADS * EDIM) sW[tid] = We[tid];
        if (tid < HEADS) sb[tid] = be[tid];
        __syncthreads();

        const int e = (blockIdx.x - PROJ_BLOCKS) * 256 + tid;
        if (e >= EDGES) return;

        const int src = ei[e];
        const int tgt = ei[EDGES + e];
        float4 a0 = *reinterpret_cast<const float4*>(ea + (size_t)e * EDIM);
        float4 a1 = *reinterpret_cast<const float4*>(ea + (size_t)e * EDIM + 4);

        float g[HEADS];
        #pragma unroll
        for (int h = 0; h < HEADS; ++h) {
            const float* w = &sW[h * EDIM];
            float z = sb[h]
                    + a0.x * w[0] + a0.y * w[1] + a0.z * w[2] + a0.w * w[3]
                    + a1.x * w[4] + a1.y * w[5] + a1.z * w[6] + a1.w * w[7];
            g[h] = 1.0f / (1.0f + __expf(-z));
        }

        int nx = atomicExch(&head4[tgt * 4 + (e & 3)], e);

        uint4 r0, r1;
        r0.x = (u32)nx;
        r0.y = (u32)src;
        r0.z = packbf(g[0], g[1]);
        r0.w = packbf(g[2], g[3]);
        r1.x = packbf(g[4], g[5]);
        r1.y = packbf(g[6], g[7]);
        r1.z = 0; r1.w = 0;
        rec[(size_t)e * 2 + 0] = r0;      // coalesced 32B
        rec[(size_t)e * 2 + 1] = r1;
    }
}

// ---------------------------------------------------------------------------
// aggregate_v7: 16-lane group per node walks FOUR chains concurrently
// (branchless: clamped index + masked accumulate). 4x memory-level
// parallelism on the serial rec-chain; serial iterations = max sublist
// length (~5) instead of full degree (~8, max-of-group ~12).
// ---------------------------------------------------------------------------
__global__ __launch_bounds__(256) void aggregate_v7(const u16* __restrict__ xpb,
                                                    const int* __restrict__ head4,
                                                    const char* __restrict__ recB,
                                                    float* __restrict__ out) {
    const int n = blockIdx.x * 16 + (threadIdx.x >> 4);
    if (n >= NODES) return;
    const int l = threadIdx.x & 15;    // lane in group
    const int h = l >> 1;              // head for this lane's 8 cols

    float acc[8];
    #pragma unroll
    for (int i = 0; i < 8; ++i) acc[i] = 0.0f;

    int e0 = head4[n * 4 + 0];
    int e1 = head4[n * 4 + 1];
    int e2 = head4[n * 4 + 2];
    int e3 = head4[n * 4 + 3];

    while (e0 >= 0 || e1 >= 0 || e2 >= 0 || e3 >= 0) {
        int c0 = e0 >= 0 ? e0 : 0;
        int c1 = e1 >= 0 ? e1 : 0;
        int c2 = e2 >= 0 ? e2 : 0;
        int c3 = e3 >= 0 ? e3 : 0;
        const char* r0 = recB + (size_t)c0 * 32;
        const char* r1 = recB + (size_t)c1 * 32;
        const char* r2 = recB + (size_t)c2 * 32;
        const char* r3 = recB + (size_t)c3 * 32;
        int2 ns0 = *reinterpret_cast<const int2*>(r0);
        int2 ns1 = *reinterpret_cast<const int2*>(r1);
        int2 ns2 = *reinterpret_cast<const int2*>(r2);
        int2 ns3 = *reinterpret_cast<const int2*>(r3);
        float g0 = bf2f(*reinterpret_cast<const u16*>(r0 + 8 + 2 * h));
        float g1 = bf2f(*reinterpret_cast<const u16*>(r1 + 8 + 2 * h));
        float g2 = bf2f(*reinterpret_cast<const u16*>(r2 + 8 + 2 * h));
        float g3 = bf2f(*reinterpret_cast<const u16*>(r3 + 8 + 2 * h));
        short8 u0 = *reinterpret_cast<const short8*>(xpb + (size_t)ns0.y * DIM + l * 8);
        short8 u1 = *reinterpret_cast<const short8*>(xpb + (size_t)ns1.y * DIM + l * 8);
        short8 u2 = *reinterpret_cast<const short8*>(xpb + (size_t)ns2.y * DIM + l * 8);
        short8 u3 = *reinterpret_cast<const short8*>(xpb + (size_t)ns3.y * DIM + l * 8);
        float m0 = e0 >= 0 ? g0 : 0.0f;
        float m1 = e1 >= 0 ? g1 : 0.0f;
        float m2 = e2 >= 0 ? g2 : 0.0f;
        float m3 = e3 >= 0 ? g3 : 0.0f;
        #pragma unroll
        for (int i = 0; i < 8; ++i) {
            acc[i] += m0 * bf2f((u16)u0[i]);
            acc[i] += m1 * bf2f((u16)u1[i]);
            acc[i] += m2 * bf2f((u16)u2[i]);
            acc[i] += m3 * bf2f((u16)u3[i]);
        }
        e0 = e0 >= 0 ? ns0.x : -1;
        e1 = e1 >= 0 ? ns1.x : -1;
        e2 = e2 >= 0 ? ns2.x : -1;
        e3 = e3 >= 0 ? ns3.x : -1;
    }

    float4 o0 = {acc[0], acc[1], acc[2], acc[3]};
    float4 o1 = {acc[4], acc[5], acc[6], acc[7]};
    float4* op = reinterpret_cast<float4*>(out + (size_t)n * DIM + l * 8);
    op[0] = o0;
    op[1] = o1;
}

// ---------------------------------------------------------------------------
// Fallback (small ws): per-edge atomic scatter reading bf16 xp
// ---------------------------------------------------------------------------
__global__ __launch_bounds__(256) void edge_scatter(const int* __restrict__ ei,
                                                    const float* __restrict__ ea,
                                                    const float* __restrict__ We,
                                                    const float* __restrict__ be,
                                                    const u16* __restrict__ xpb,
                                                    float* __restrict__ out) {
    __shared__ float sW[HEADS * EDIM];
    __shared__ float sb[HEADS];
    if (threadIdx.x < HEADS * EDIM) sW[threadIdx.x] = We[threadIdx.x];
    if (threadIdx.x < HEADS) sb[threadIdx.x] = be[threadIdx.x];
    __syncthreads();

    const int t = blockIdx.x * 256 + threadIdx.x;
    const int e = t >> 5;
    const int l = t & 31;
    if (e >= EDGES) return;

    const int src = ei[e];
    const int tgt = ei[EDGES + e];
    const int h = l >> 2;

    float4 ea0 = *reinterpret_cast<const float4*>(ea + (size_t)e * EDIM);
    float4 ea1 = *reinterpret_cast<const float4*>(ea + (size_t)e * EDIM + 4);
    float4 wa = *reinterpret_cast<const float4*>(&sW[h * EDIM]);
    float4 wb = *reinterpret_cast<const float4*>(&sW[h * EDIM + 4]);
    float z = sb[h]
            + ea0.x * wa.x + ea0.y * wa.y + ea0.z * wa.z + ea0.w * wa.w
            + ea1.x * wb.x + ea1.y * wb.y + ea1.z * wb.z + ea1.w * wb.w;
    float g = 1.0f / (1.0f + __expf(-z));

    ushort4 u = *reinterpret_cast<const ushort4*>(xpb + (size_t)src * DIM + l * 4);
    float* op = out + (size_t)tgt * DIM + l * 4;
    unsafeAtomicAdd(op + 0, bf2f(u.x) * g);
    unsafeAtomicAdd(op + 1, bf2f(u.y) * g);
    unsafeAtomicAdd(op + 2, bf2f(u.z) * g);
    unsafeAtomicAdd(op + 3, bf2f(u.w) * g);
}

// ---------------------------------------------------------------------------
extern "C" void kernel_launch(void* const* d_in, const int* in_sizes, int n_in,
                              void* d_out, int out_size, void* d_ws, size_t ws_size,
                              hipStream_t stream) {
    const float* x   = (const float*)d_in[0];
    const int*   ei  = (const int*)d_in[1];
    const float* eat = (const float*)d_in[2];
    const float* Wn  = (const float*)d_in[3];
    const float* bn  = (const float*)d_in[4];
    const float* We  = (const float*)d_in[5];
    const float* be  = (const float*)d_in[6];
    float* out = (float*)d_out;

    // workspace layout (all segments 16B-aligned)
    u16* xpb   = (u16*)d_ws;                                // NODES*128 bf16 (25.6MB)
    int* head4 = (int*)(xpb + (size_t)NODES * DIM);         // NODES*4 i32 (1.6MB)
    char* rec  = (char*)(head4 + (size_t)NODES * 4);        // EDGES*32 B (25.6MB)

    const size_t need = (size_t)NODES * DIM * 2 + (size_t)NODES * 16
                      + (size_t)EDGES * 32;                 // ~52.8 MB
    const size_t need_fb = (size_t)NODES * DIM * 2;         // fallback: xpb only

    if (ws_size >= need) {
        hipMemsetAsync(head4, 0xFF, (size_t)NODES * 16, stream);  // head4 = -1
        prep_fused<<<PROJ_BLOCKS + REC_BLOCKS, 256, 0, stream>>>(
            x, Wn, bn, ei, eat, We, be, head4, (uint4*)rec, xpb);
        aggregate_v7<<<(NODES + 15) / 16, 256, 0, stream>>>(xpb, head4, rec, out);
    } else if (ws_size >= need_fb) {
        // fallback: proj-only (rec blocks omitted), then atomic scatter
        prep_fused<<<PROJ_BLOCKS, 256, 0, stream>>>(
            x, Wn, bn, ei, eat, We, be, nullptr, nullptr, xpb);
        hipMemsetAsync(d_out, 0, (size_t)out_size * sizeof(float), stream);
        edge_scatter<<<(EDGES * 32) / 256, 256, 0, stream>>>(ei, eat, We, be, xpb, out);
    }
}